// Round 4
// baseline (437.561 us; speedup 1.0000x reference)
//
#include <hip/hip_runtime.h>
#include <hip/hip_bf16.h>
#include <stdint.h>

#define HWSZ 16384
#define CCH 192
#define NB 8
#define NHEAD 4
#define DHEAD 48

typedef unsigned short u16;
typedef __bf16 bf16x8 __attribute__((ext_vector_type(8)));
typedef float f32x4 __attribute__((ext_vector_type(4)));
typedef short s16x8 __attribute__((ext_vector_type(8)));
typedef short s16x4 __attribute__((ext_vector_type(4)));

__device__ __forceinline__ float b2f(u16 h){
  union { unsigned u; float f; } v; v.u = ((unsigned)h) << 16; return v.f;
}
__device__ __forceinline__ u16 f2b(float f){
  union { float f; unsigned u; } v; v.f = f;
  unsigned r = v.u + 0x7fffu + ((v.u >> 16) & 1u);
  return (u16)(r >> 16);
}

// ---------------------------------------------------------------------------
// K0: pack w_q,w_k,w_v (f32 192x192) to bf16 once (L2-resident for k_lngemm).
// ---------------------------------------------------------------------------
__global__ __launch_bounds__(256) void k_wpack(
    const float* __restrict__ wq, const float* __restrict__ wk,
    const float* __restrict__ wv, u16* __restrict__ o)
{
  int m = blockIdx.x;
  const float* src = (m == 0) ? wq : (m == 1) ? wk : wv;
  u16* dst = o + (size_t)m * CCH * CCH;
  int tid = threadIdx.x;
  #pragma unroll
  for (int i = 0; i < 36; ++i){
    int e = (i * 256 + tid) * 4;
    float4 v = *(const float4*)(src + e);
    s16x4 pk;
    pk[0] = (short)f2b(v.x); pk[1] = (short)f2b(v.y);
    pk[2] = (short)f2b(v.z); pk[3] = (short)f2b(v.w);
    *(s16x4*)(dst + e) = pk;
  }
}

// ---------------------------------------------------------------------------
// K1 v2: fused LayerNorm + conv1x1 GEMM(s), latency-optimized.
// x-values held in registers end-to-end; f32 partial stats in regs -> 8KB LDS
// reduce; normalized bf16 written ONCE into 16x16-subtiled layout read via
// ds_read_b64_tr_b16 (conflict-light both sides). LDS 34.8KB -> 4 blk/CU.
// ---------------------------------------------------------------------------
template<int NG>
__global__ __launch_bounds__(256) void k_lngemm(
    const float* __restrict__ x, const float* __restrict__ lnw,
    const float* __restrict__ lnb,
    const u16* __restrict__ W0, const u16* __restrict__ W1,
    u16* __restrict__ O0, u16* __restrict__ O1)
{
  __shared__ u16 lnT[12672];        // subtiled bf16: [kb6][nt4][tile2][264]
  __shared__ float red[2048];       // partial s [16][64]; ss at +1024
  __shared__ float mures[128];      // mu[64], rstd[64]
  __shared__ float lwlb[384];       // lnw[192], lnb[192]
  int tid = threadIdx.x;
  int b   = blockIdx.y;
  int p0  = blockIdx.x * 64;
  int cq  = tid >> 4;               // channel sub-index 0..15
  int q   = tid & 15;               // px quad 0..15

  float wl = 0.f, bl = 0.f;
  if (tid >= 64){
    int c = tid - 64;
    wl = lnw[c]; bl = lnb[c];
  }

  // Phase A: 12 independent float4 loads (c = 16i+cq, px = 4q..4q+3), held in
  // registers; f32 partial stats accumulated componentwise.
  float4 v[12];
  {
    const float* xb = x + (size_t)b * CCH * HWSZ + p0;
    #pragma unroll
    for (int i = 0; i < 12; ++i)
      v[i] = *(const float4*)(xb + (size_t)(i * 16 + cq) * HWSZ + q * 4);
  }
  {
    float4 ps  = make_float4(0.f, 0.f, 0.f, 0.f);
    float4 pss = make_float4(0.f, 0.f, 0.f, 0.f);
    #pragma unroll
    for (int i = 0; i < 12; ++i){
      ps.x += v[i].x; ps.y += v[i].y; ps.z += v[i].z; ps.w += v[i].w;
      pss.x += v[i].x * v[i].x; pss.y += v[i].y * v[i].y;
      pss.z += v[i].z * v[i].z; pss.w += v[i].w * v[i].w;
    }
    *(float4*)(&red[cq * 64 + q * 4])        = ps;
    *(float4*)(&red[1024 + cq * 64 + q * 4]) = pss;
  }
  __syncthreads();

  // Phase B: finalize per-pixel stats (64 threads); others stage lw/lb.
  if (tid < 64){
    float s = 0.f, ss2 = 0.f;
    #pragma unroll
    for (int j = 0; j < 16; ++j){
      s   += red[j * 64 + tid];
      ss2 += red[1024 + j * 64 + tid];
    }
    float mu  = s * (1.f / CCH);
    float var = ss2 * (1.f / CCH) - mu * mu;
    mures[tid]      = mu;
    mures[64 + tid] = rsqrtf(var + 1e-5f);
  } else {
    int c = tid - 64;
    lwlb[c] = wl; lwlb[192 + c] = bl;
  }
  __syncthreads();

  // Phase C: normalize from registers -> bf16 subtiled LDS (ds_write_b64).
  {
    float m0 = mures[q * 4 + 0], m1 = mures[q * 4 + 1];
    float m2 = mures[q * 4 + 2], m3 = mures[q * 4 + 3];
    float r0 = mures[64 + q * 4 + 0], r1 = mures[64 + q * 4 + 1];
    float r2 = mures[64 + q * 4 + 2], r3 = mures[64 + q * 4 + 3];
    #pragma unroll
    for (int i = 0; i < 12; ++i){
      int c = i * 16 + cq;
      float lw_ = lwlb[c], lb_ = lwlb[192 + c];
      s16x4 pk;
      pk[0] = (short)f2b((v[i].x - m0) * r0 * lw_ + lb_);
      pk[1] = (short)f2b((v[i].y - m1) * r1 * lw_ + lb_);
      pk[2] = (short)f2b((v[i].z - m2) * r2 * lw_ + lb_);
      pk[3] = (short)f2b((v[i].w - m3) * r3 * lw_ + lb_);
      int kb   = c >> 5, kr = c & 31;
      int tile = (kr >> 2) & 1;
      int mr   = ((kr >> 3) << 2) | (kr & 3);
      int ti   = (kb * 4 + (q >> 2)) * 2 + tile;
      *(s16x4*)(&lnT[ti * 264 + mr * 16 + (q & 3) * 4]) = pk;
    }
  }
  __syncthreads();

  // GEMM phase: wave owns M-rows [wid*48, +48); B-fragments via tr-read.
  int lane = tid & 63, wid = tid >> 6;
  int quad = lane >> 4, r = lane & 15;
  int wm = wid * 48;
  const u16* A0 = W0 + (size_t)wm * CCH;
  const u16* A1 = (NG == 2) ? (W1 + (size_t)wm * CCH) : nullptr;
  f32x4 acc0[3][4] = {};
  f32x4 acc1[3][4] = {};
  unsigned lvb = (unsigned)(uintptr_t)(&lnT[0]) + 2u * (unsigned)(r + quad * 64);
  #pragma unroll
  for (int kb = 0; kb < 6; ++kb){
    int k0 = kb * 32;
    bf16x8 a0[3], a1[3];
    #pragma unroll
    for (int i = 0; i < 3; ++i)
      a0[i] = *(const bf16x8*)(A0 + (size_t)(i * 16 + r) * CCH + k0 + quad * 8);
    if (NG == 2){
      #pragma unroll
      for (int i = 0; i < 3; ++i)
        a1[i] = *(const bf16x8*)(A1 + (size_t)(i * 16 + r) * CCH + k0 + quad * 8);
    }
    s16x4 lo[4], hi[4];
    #pragma unroll
    for (int j = 0; j < 4; ++j){
      unsigned a = lvb + (unsigned)kb * 4224u + (unsigned)j * 1056u;
      asm volatile("ds_read_b64_tr_b16 %0, %1" : "=&v"(lo[j]) : "v"(a));
      asm volatile("ds_read_b64_tr_b16 %0, %1 offset:528" : "=&v"(hi[j]) : "v"(a));
    }
    asm volatile("s_waitcnt lgkmcnt(0)" ::: "memory");
    __builtin_amdgcn_sched_barrier(0);
    #pragma unroll
    for (int j = 0; j < 4; ++j){
      union { s16x8 s; bf16x8 b; } u;
      u.s = __builtin_shufflevector(lo[j], hi[j], 0, 1, 2, 3, 4, 5, 6, 7);
      #pragma unroll
      for (int i = 0; i < 3; ++i)
        acc0[i][j] = __builtin_amdgcn_mfma_f32_16x16x32_bf16(a0[i], u.b, acc0[i][j], 0, 0, 0);
      if (NG == 2){
        #pragma unroll
        for (int i = 0; i < 3; ++i)
          acc1[i][j] = __builtin_amdgcn_mfma_f32_16x16x32_bf16(a1[i], u.b, acc1[i][j], 0, 0, 0);
      }
    }
  }
  size_t ob = (size_t)b * CCH * HWSZ;
  #pragma unroll
  for (int i = 0; i < 3; ++i){
    #pragma unroll
    for (int rg = 0; rg < 4; ++rg){
      int o = wm + i * 16 + quad * 4 + rg;
      size_t rowb = ob + (size_t)o * HWSZ;
      #pragma unroll
      for (int j = 0; j < 4; ++j){
        int n = p0 + j * 16 + r;
        O0[rowb + n] = f2b(acc0[i][j][rg]);
        if (NG == 2) O1[rowb + n] = f2b(acc1[i][j][rg]);
      }
    }
  }
}

// ---------------------------------------------------------------------------
// K3: depthwise 3x3, register-rolling (no LDS). Thread = 8x8 px patch;
// 10 row loads up front (ILP), one __syncthreads (vmcnt drain) for in-place
// safety, halo via __shfl.
// ---------------------------------------------------------------------------
__global__ __launch_bounds__(256) void k_dw3(
    const float* __restrict__ wq, const float* __restrict__ wk,
    const float* __restrict__ wv,
    u16* __restrict__ bq, u16* __restrict__ bk, u16* __restrict__ bv,
    float* __restrict__ ssq_q, float* __restrict__ ssq_k)
{
  int tid = threadIdx.x;
  int bc  = blockIdx.x;                 // b*192 + c
  int z   = blockIdx.y;                 // 0=q 1=k 2=v
  int c   = bc % CCH;
  const float* wd = (z == 0) ? wq : (z == 1) ? wk : wv;
  u16* buf = (z == 0) ? bq : (z == 1) ? bk : bv;
  float w[9];
  #pragma unroll
  for (int t = 0; t < 9; ++t) w[t] = wd[c * 9 + t];
  u16* p = buf + (size_t)bc * HWSZ;

  int xseg = tid & 15, ygrp = tid >> 4;
  int x0 = xseg * 8, y0 = ygrp * 8;

  s16x8 zz = {0,0,0,0,0,0,0,0};
  s16x8 raw[10];
  #pragma unroll
  for (int rr = 0; rr < 10; ++rr){
    int yy = y0 - 1 + rr;
    raw[rr] = (yy >= 0 && yy < 128) ? *(const s16x8*)(p + yy * 128 + x0) : zz;
  }
  __syncthreads();

  float cf[10][8];
  float lf[10], rgt[10];
  #pragma unroll
  for (int rr = 0; rr < 10; ++rr){
    #pragma unroll
    for (int j = 0; j < 8; ++j) cf[rr][j] = b2f((u16)raw[rr][j]);
    float l  = __shfl_up(cf[rr][7], 1);
    float rr_ = __shfl_down(cf[rr][0], 1);
    lf[rr]  = (xseg > 0)  ? l   : 0.f;
    rgt[rr] = (xseg < 15) ? rr_ : 0.f;
  }

  float ss = 0.f;
  #pragma unroll
  for (int k = 0; k < 8; ++k){
    float acc[8] = {0.f,0.f,0.f,0.f,0.f,0.f,0.f,0.f};
    #pragma unroll
    for (int dy = 0; dy < 3; ++dy){
      int rr = k + dy;
      float wl = w[dy * 3], wc = w[dy * 3 + 1], wr = w[dy * 3 + 2];
      acc[0] += wl * lf[rr] + wc * cf[rr][0] + wr * cf[rr][1];
      #pragma unroll
      for (int j = 1; j < 7; ++j)
        acc[j] += wl * cf[rr][j - 1] + wc * cf[rr][j] + wr * cf[rr][j + 1];
      acc[7] += wl * cf[rr][6] + wc * cf[rr][7] + wr * rgt[rr];
    }
    s16x8 pk;
    #pragma unroll
    for (int j = 0; j < 8; ++j){
      pk[j] = (short)f2b(acc[j]);
      ss += acc[j] * acc[j];
    }
    *(s16x8*)(p + (y0 + k) * 128 + x0) = pk;
  }

  if (z < 2){
    #pragma unroll
    for (int m = 32; m > 0; m >>= 1) ss += __shfl_xor(ss, m);
    if ((tid & 63) == 0) atomicAdd(&((z == 0) ? ssq_q : ssq_k)[bc], ss);
  }
}

// ---------------------------------------------------------------------------
// K4: raw gram G[b][h][c][d] += sum_n q[c,n]*k[d,n], split-K (16 chunks),
// MFMA fragments straight from global; 4-wave LDS reduce then atomicAdd.
// ---------------------------------------------------------------------------
__global__ void k_gram(const u16* __restrict__ q, const u16* __restrict__ k,
                       float* __restrict__ G)
{
  __shared__ float gs[4 * 48 * 49];     // padded rows (49) to spread banks
  int tid = threadIdx.x;
  int chunk = blockIdx.x;
  int h = blockIdx.y, b = blockIdx.z;
  int lane = tid & 63, w = tid >> 6;
  int quad = lane >> 4, r = lane & 15;
  int nb = chunk * 1024 + w * 256;
  const u16* qb = q + ((size_t)b * CCH + h * DHEAD) * HWSZ;
  const u16* kb = k + ((size_t)b * CCH + h * DHEAD) * HWSZ;
  f32x4 acc[3][3] = {};
  for (int s = 0; s < 8; ++s){
    int kk = nb + s * 32 + quad * 8;
    bf16x8 af[3], bfr[3];
    #pragma unroll
    for (int i = 0; i < 3; ++i){
      af[i]  = *(const bf16x8*)(qb + (size_t)(i * 16 + r) * HWSZ + kk);
      bfr[i] = *(const bf16x8*)(kb + (size_t)(i * 16 + r) * HWSZ + kk);
    }
    #pragma unroll
    for (int i = 0; i < 3; ++i)
      #pragma unroll
      for (int j = 0; j < 3; ++j)
        acc[i][j] = __builtin_amdgcn_mfma_f32_16x16x32_bf16(af[i], bfr[j], acc[i][j], 0, 0, 0);
  }
  float* gw = gs + w * (48 * 49);
  #pragma unroll
  for (int i = 0; i < 3; ++i)
    #pragma unroll
    for (int j = 0; j < 3; ++j)
      #pragma unroll
      for (int rg = 0; rg < 4; ++rg){
        int row = i * 16 + quad * 4 + rg;
        int col = j * 16 + r;
        gw[row * 49 + col] = acc[i][j][rg];
      }
  __syncthreads();
  float* gb = G + (size_t)(b * NHEAD + h) * (DHEAD * DHEAD);
  #pragma unroll
  for (int t = 0; t < 9; ++t){
    int e = t * 256 + tid;              // 0..2303
    int row = e / 48, col = e - row * 48;
    int o = row * 49 + col;
    float s = gs[o] + gs[48 * 49 + o] + gs[2 * 48 * 49 + o] + gs[3 * 48 * 49 + o];
    atomicAdd(&gb[e], s);
  }
}

// ---------------------------------------------------------------------------
// K5: per (b,h) build M-slice = Wp[:, h*48:+48] @ P_h  (192x48, bf16)
// where P_h = softmax(G * rq*rk*temp). M is the fused (proj @ blockdiag(P)).
// ---------------------------------------------------------------------------
__global__ __launch_bounds__(256) void k_mk(
    const float* __restrict__ G, const float* __restrict__ ssq_q,
    const float* __restrict__ ssq_k, const float* __restrict__ temp,
    const float* __restrict__ wp, u16* __restrict__ Mout)
{
  __shared__ u16 Pt[48 * 72];     // P^T rows d, cols c (pad 48->72, zeros)
  __shared__ u16 wA[192 * 72];    // Wp head-slice rows o, cols c (pad zeros)
  __shared__ float rks[48];
  int tid = threadIdx.x;
  int h = blockIdx.x, b = blockIdx.y;
  {
    s16x8 z = {};
    #pragma unroll
    for (int i = 0; i < 2; ++i){
      int idx = (i * 256 + tid) * 8;
      if (idx < 48 * 72) *(s16x8*)(&Pt[idx]) = z;
    }
    #pragma unroll
    for (int i = 0; i < 7; ++i){
      int idx = (i * 256 + tid) * 8;
      if (idx < 192 * 72) *(s16x8*)(&wA[idx]) = z;
    }
  }
  if (tid < DHEAD)
    rks[tid] = 1.f / fmaxf(sqrtf(ssq_k[b * CCH + h * DHEAD + tid]), 1e-12f);
  __syncthreads();
  if (tid < DHEAD){
    float rq = temp[h] / fmaxf(sqrtf(ssq_q[b * CCH + h * DHEAD + tid]), 1e-12f);
    const float* gr = G + (size_t)(b * NHEAD + h) * (DHEAD * DHEAD) + tid * DHEAD;
    float a[DHEAD];
    float mx = -1e30f;
    #pragma unroll
    for (int d = 0; d < DHEAD; ++d){
      a[d] = gr[d] * rq * rks[d];
      mx = fmaxf(mx, a[d]);
    }
    float sum = 0.f;
    #pragma unroll
    for (int d = 0; d < DHEAD; ++d){ a[d] = __expf(a[d] - mx); sum += a[d]; }
    float inv = 1.f / sum;
    #pragma unroll
    for (int d = 0; d < DHEAD; ++d) Pt[d * 72 + tid] = f2b(a[d] * inv);
  }
  {
    const float* wb = wp + h * DHEAD;
    #pragma unroll
    for (int i = 0; i < 9; ++i){
      int e = (i * 256 + tid) * 4;       // 9216 = 192*48
      int row = e / DHEAD, col = e - row * DHEAD;
      float4 v = *(const float4*)(wb + (size_t)row * CCH + col);
      s16x4 pk;
      pk[0] = (short)f2b(v.x); pk[1] = (short)f2b(v.y);
      pk[2] = (short)f2b(v.z); pk[3] = (short)f2b(v.w);
      *(s16x4*)(&wA[row * 72 + col]) = pk;
    }
  }
  __syncthreads();
  int lane = tid & 63, wid = tid >> 6;
  int quad = lane >> 4, r = lane & 15;
  int wm = wid * 48;
  f32x4 acc[3][3] = {};
  #pragma unroll
  for (int ks = 0; ks < 2; ++ks){
    int k0 = ks * 32;
    bf16x8 af[3], bf[3];
    #pragma unroll
    for (int i = 0; i < 3; ++i)
      af[i] = *(const bf16x8*)(&wA[(wm + i * 16 + r) * 72 + k0 + quad * 8]);
    #pragma unroll
    for (int j = 0; j < 3; ++j)
      bf[j] = *(const bf16x8*)(&Pt[(j * 16 + r) * 72 + k0 + quad * 8]);
    #pragma unroll
    for (int i = 0; i < 3; ++i)
      #pragma unroll
      for (int j = 0; j < 3; ++j)
        acc[i][j] = __builtin_amdgcn_mfma_f32_16x16x32_bf16(af[i], bf[j], acc[i][j], 0, 0, 0);
  }
  u16* mb = Mout + (size_t)b * (CCH * CCH) + h * DHEAD;
  #pragma unroll
  for (int i = 0; i < 3; ++i)
    #pragma unroll
    for (int j = 0; j < 3; ++j)
      #pragma unroll
      for (int rg = 0; rg < 4; ++rg){
        int o = wm + i * 16 + quad * 4 + rg;
        int d = j * 16 + r;
        mb[(size_t)o * CCH + d] = f2b(acc[i][j][rg]);
      }
}

// ---------------------------------------------------------------------------
// K6: fused attention+proj GEMM  Out[b][o][n] = sum_c M[b][o][c]*V[b][c][n]
// + resid.  B-fragments via ds_read_b64_tr_b16 from 16x16-subtiled LDS.
// ---------------------------------------------------------------------------
__global__ __launch_bounds__(256) void k_gemmv(
    const u16* __restrict__ M, const u16* __restrict__ V,
    float* __restrict__ Out, const float* __restrict__ resid)
{
  __shared__ u16 lA[64 * 200];     // M slice rows
  __shared__ u16 lV[96 * 264];     // 6kb x 8nb x 2 tiles of 16x16 (+8 pad)
  int tid = threadIdx.x;
  int n0 = blockIdx.x * 128;
  int m0 = blockIdx.y * 64;
  int b  = blockIdx.z;
  {
    const u16* ap = M + (size_t)b * (CCH * CCH) + m0 * CCH;
    #pragma unroll
    for (int i = 0; i < 6; ++i){
      int off = (i * 256 + tid) * 8;
      int row = off / CCH, col = off - row * CCH;
      *(int4*)(&lA[row * 200 + col]) = *(const int4*)(ap + off);
    }
  }
  {
    const u16* vp = V + (size_t)b * CCH * HWSZ + n0;
    #pragma unroll
    for (int i = 0; i < 12; ++i){
      int e = i * 256 + tid;          // 3072 = 192c x 16 groups
      int c = e >> 4, ns = (e & 15) * 8;
      int4 v = *(const int4*)(vp + (size_t)c * HWSZ + ns);
      int kb = c >> 5, kr = c & 31;
      int tile = (kr >> 2) & 1;
      int mr = ((kr >> 3) << 2) | (kr & 3);
      int ti = (kb * 8 + (ns >> 4)) * 2 + tile;
      *(int4*)(&lV[ti * 264 + mr * 16 + (ns & 15)]) = v;
    }
  }
  __syncthreads();
  int lane = tid & 63, wid = tid >> 6;
  int quad = lane >> 4, r = lane & 15;
  int wm = (wid >> 1) * 32, wn = (wid & 1) * 64;
  unsigned lvb = (unsigned)(uintptr_t)(&lV[0]) + 2u * (unsigned)(r + quad * 64)
               + (unsigned)((wn >> 4) * 2) * 528u;
  f32x4 acc[2][4] = {};
  #pragma unroll
  for (int kb = 0; kb < 6; ++kb){
    int k0 = kb * 32;
    s16x4 lo[4], hi[4];
    #pragma unroll
    for (int j = 0; j < 4; ++j){
      unsigned a = lvb + (unsigned)kb * 8448u + (unsigned)j * 1056u;
      asm volatile("ds_read_b64_tr_b16 %0, %1" : "=&v"(lo[j]) : "v"(a));
      asm volatile("ds_read_b64_tr_b16 %0, %1 offset:528" : "=&v"(hi[j]) : "v"(a));
    }
    bf16x8 af[2];
    #pragma unroll
    for (int i = 0; i < 2; ++i)
      af[i] = *(const bf16x8*)(&lA[(wm + i * 16 + r) * 200 + k0 + quad * 8]);
    asm volatile("s_waitcnt lgkmcnt(0)" ::: "memory");
    __builtin_amdgcn_sched_barrier(0);
    #pragma unroll
    for (int j = 0; j < 4; ++j){
      union { s16x8 s; bf16x8 b; } u;
      u.s = __builtin_shufflevector(lo[j], hi[j], 0, 1, 2, 3, 4, 5, 6, 7);
      #pragma unroll
      for (int i = 0; i < 2; ++i)
        acc[i][j] = __builtin_amdgcn_mfma_f32_16x16x32_bf16(af[i], u.b, acc[i][j], 0, 0, 0);
    }
  }
  size_t obase = (size_t)b * CCH * HWSZ;
  #pragma unroll
  for (int i = 0; i < 2; ++i){
    #pragma unroll
    for (int rg = 0; rg < 4; ++rg){
      int o = m0 + wm + i * 16 + quad * 4 + rg;
      size_t rowb = obase + (size_t)o * HWSZ;
      #pragma unroll
      for (int j = 0; j < 4; ++j){
        int n = n0 + wn + j * 16 + r;
        Out[rowb + n] = acc[i][j][rg] + resid[rowb + n];
      }
    }
  }
}

// ---------------------------------------------------------------------------
extern "C" void kernel_launch(void* const* d_in, const int* in_sizes, int n_in,
                              void* d_out, int out_size, void* d_ws, size_t ws_size,
                              hipStream_t stream)
{
  const float* xx     = (const float*)d_in[0];
  const float* q_in   = (const float*)d_in[1];
  const float* ln_w   = (const float*)d_in[2];
  const float* ln_b   = (const float*)d_in[3];
  const float* w_q    = (const float*)d_in[4];
  const float* w_k    = (const float*)d_in[5];
  const float* w_v    = (const float*)d_in[6];
  const float* wd_q   = (const float*)d_in[7];
  const float* wd_k   = (const float*)d_in[8];
  const float* wd_v   = (const float*)d_in[9];
  const float* w_proj = (const float*)d_in[10];
  const float* temp   = (const float*)d_in[11];

  const size_t SZ = (size_t)NB * CCH * HWSZ;
  u16* B1 = (u16*)d_ws;                          // v_conv -> v_dw (in-place)
  u16* B2 = B1 + SZ;                             // k_conv -> k_dw (in-place)
  u16* B3 = B2 + SZ;                             // q_conv -> q_dw (in-place)
  float* G     = (float*)(B3 + SZ);
  float* ssq_q = G + 32 * DHEAD * DHEAD;
  float* ssq_k = ssq_q + NB * CCH;
  u16* Mb      = (u16*)(ssq_k + NB * CCH);       // fused proj matrices
  u16* Wb      = Mb + (size_t)NB * CCH * CCH;    // packed bf16 weights q,k,v

  hipMemsetAsync(G, 0, (size_t)(32 * DHEAD * DHEAD + 2 * NB * CCH) * sizeof(float), stream);

  k_wpack<<<3, 256, 0, stream>>>(w_q, w_k, w_v, Wb);
  // fused LN(xx) + {k,v} conv GEMMs; fused LN(q_in) + q conv GEMM
  k_lngemm<2><<<dim3(256, NB), 256, 0, stream>>>(
      xx, ln_w, ln_b, Wb + CCH * CCH, Wb + 2 * CCH * CCH, B2, B1);
  k_lngemm<1><<<dim3(256, NB), 256, 0, stream>>>(
      q_in, ln_w, ln_b, Wb, nullptr, B3, nullptr);
  // merged depthwise: q in B3, k in B2, v in B1 — all in-place
  k_dw3<<<dim3(NB * CCH, 3), 256, 0, stream>>>(wd_q, wd_k, wd_v,
                                               B3, B2, B1, ssq_q, ssq_k);
  k_gram<<<dim3(16, NHEAD, NB), 256, 0, stream>>>(B3, B2, G);
  // fold softmax+proj into per-batch 192x192 matrix M
  k_mk<<<dim3(NHEAD, NB), 256, 0, stream>>>(G, ssq_q, ssq_k, temp, w_proj, Mb);
  // out = M @ V + q_in  (single fused GEMM)
  k_gemmv<<<dim3(128, 3, NB), 256, 0, stream>>>(Mb, B1, (float*)d_out, q_in);
}